// Round 5
// baseline (143.171 us; speedup 1.0000x reference)
//
#include <hip/hip_runtime.h>

// ImplicitFunction MLP via fp16 MFMA, round 5: persistent register-resident
// weights, zero LDS.
//
// Round-4 diagnosis: 106 ds_read_b128 per 64-point batch (W frags + bias
// C-operands) ~= 34us of CU-shared LDS port time — the real bottleneck.
// This round: the whole 50KB fp16 weight-fragment image lives in each wave's
// registers (gfx950 unified 512-reg file). Grid = 1024 one-wave blocks; each
// wave processes 16 batches of 64 points (grid-stride). Steady-state loop has
// NO LDS and no barriers.
//
// Bias handling without LDS:
//  - layer 0: bias in the unused k=3 slot of W0 (B-operand gets constant 1).
//  - hidden layers: bc = mfma(biasF_l, oneF, 0) broadcasts bias[m] to all
//    points in C-layout; used as C-init. 2 extra MFMAs/layer << 8 ds_reads.
//
// Math (as round 4): activations scaled 1/64; K-permuted weights make the
// layer transition exchange-free; lrelu in packed fp16.
// Layouts (gfx950, 32x32x16):
//   A/B frag: lane (i=lane&31, h=lane>>5) holds k = 8h+j, j=0..7
//   C/D:      col n = lane&31, row m = (r&3) + 8*(r>>2) + 4h, r=0..15

typedef _Float16 half8 __attribute__((ext_vector_type(8)));
typedef _Float16 half2v __attribute__((ext_vector_type(2)));
typedef float floatx16 __attribute__((ext_vector_type(16)));
typedef float float2v __attribute__((ext_vector_type(2)));

#define N_HID 6
// ws byte offsets
#define OFF_A 0        // hidden W frags [l:6][t:2][s:4][lane:64][j:8] fp16 = 49152
#define OFF_B 49152    // layer0 A frags [t:2][lane:64][j:8] fp16 (bias @ k=3) = 2048
#define OFF_C 51200    // (unused this round) bias C-layout fp32             = 1792
#define OFF_D 52992    // wo*so*64 fp32, C-layout [h:2][t:2][r:16]           = 256
#define SETUP_TOTAL (24576 + 1024 + 448 + 64)

__global__ __launch_bounds__(256) void setup_weights(
    const float* __restrict__ w0, const float* __restrict__ s0, const float* __restrict__ b0,
    const float* __restrict__ wh, const float* __restrict__ sh, const float* __restrict__ bh,
    const float* __restrict__ wo, const float* __restrict__ so,
    unsigned char* __restrict__ ws)
{
    int i = blockIdx.x * 256 + threadIdx.x;
    if (i < 24576) {
        // hidden W frags, K-permutation baked in:
        // A[m][kslot(s,h,j)] = wh[l][feat][m]*sh[l][m], feat = 16s+8*(j>>2)+4h+(j&3)
        int j = i & 7, lane = (i >> 3) & 63, s = (i >> 9) & 3, t = (i >> 11) & 1, l = i >> 12;
        int m = 32 * t + (lane & 31);
        int h = lane >> 5;
        int feat = 16 * s + 8 * (j >> 2) + 4 * h + (j & 3);
        ((_Float16*)(ws + OFF_A))[i] = (_Float16)(wh[(l * 64 + feat) * 64 + m] * sh[l * 64 + m]);
    } else if (i < 24576 + 1024) {
        // layer-0 A frags; k=0..2 weights, k=3 carries bias (B supplies 1.0)
        int i2 = i - 24576;
        int j = i2 & 7, lane = (i2 >> 3) & 63, t = i2 >> 9;
        int m = 32 * t + (lane & 31);
        int k = 8 * (lane >> 5) + j;
        float v = (k < 3) ? w0[k * 64 + m] * s0[m] * 0.015625f
                          : (k == 3 ? b0[m] * 0.015625f : 0.f);
        ((_Float16*)(ws + OFF_B))[i2] = (_Float16)v;
    } else if (i < 24576 + 1024 + 448) {
        // bias C-layout (unused this round, kept for layout stability)
        int i2 = i - 24576 - 1024;
        int r = i2 & 15, t = (i2 >> 4) & 1, h = (i2 >> 5) & 1, l = i2 >> 6;
        int feat = 32 * t + (r & 3) + 8 * ((r >> 2) & 3) + 4 * h;
        float bv = (l == 0) ? b0[feat] : bh[(l - 1) * 64 + feat];
        ((float*)(ws + OFF_C))[i2] = bv * 0.015625f;
    } else if (i < SETUP_TOTAL) {
        // wo*so*64 in C layout
        int i2 = i - 24576 - 1024 - 448;
        int r = i2 & 15, t = (i2 >> 4) & 1, h = i2 >> 5;
        int feat = 32 * t + (r & 3) + 8 * ((r >> 2) & 3) + 4 * h;
        ((float*)(ws + OFF_D))[i2] = wo[feat] * so[0] * 64.f;
    }
}

union FragU { int i[4]; half8 v; };

static __device__ __forceinline__ int pkrtz(float a, float b) {
    auto hh = __builtin_amdgcn_cvt_pkrtz(a, b);
    int r;
    __builtin_memcpy(&r, &hh, 4);
    return r;
}

// packed-fp16 leaky relu: max(u, 0.2*u) -> v_pk_mul_f16 + v_pk_max_f16
static __device__ __forceinline__ int lrelu2(int v) {
    half2v u;
    __builtin_memcpy(&u, &v, 4);
    half2v w = u * (_Float16)0.2f;
    half2v r = __builtin_elementwise_max(u, w);
    int o;
    __builtin_memcpy(&o, &r, 4);
    return o;
}

static __device__ __forceinline__ floatx16 mfma16(half8 a, half8 b, floatx16 c) {
    return __builtin_amdgcn_mfma_f32_32x32x16_f16(a, b, c, 0, 0, 0);
}

__global__ __launch_bounds__(64, 1) void mlp_mfma(
    const float* __restrict__ points,
    const unsigned char* __restrict__ ws,
    const float* __restrict__ bhg,   // raw bh [6][64]
    const float* __restrict__ bo,
    float* __restrict__ out, int n)
{
    const int lane = threadIdx.x;    // one wave per block
    const int p = lane & 31;
    const int h = lane >> 5;

    // ---- persistent register state (loaded once per wave) ----
    half8 Wreg[N_HID][2][4];
    {
        const half8* WfG = (const half8*)(ws + OFF_A);
#pragma unroll
        for (int l = 0; l < N_HID; ++l)
#pragma unroll
            for (int t = 0; t < 2; ++t)
#pragma unroll
                for (int s = 0; s < 4; ++s)
                    Wreg[l][t][s] = WfG[(((l * 2 + t) * 4 + s) << 6) + lane];
    }
    half8 W0a, W0b;
    {
        const half8* A0g = (const half8*)(ws + OFF_B);
        W0a = A0g[lane];
        W0b = A0g[64 + lane];
    }
    half8 biasF[N_HID][2];
#pragma unroll
    for (int l = 0; l < N_HID; ++l)
#pragma unroll
        for (int t = 0; t < 2; ++t) {
            FragU u;
            u.i[0] = u.i[1] = u.i[2] = u.i[3] = 0;
            if (h == 0) u.v[0] = (_Float16)(bhg[l * 64 + 32 * t + p] * 0.015625f);
            biasF[l][t] = u.v;
        }
    half8 oneF;
    {
        FragU u;
        u.i[0] = u.i[1] = u.i[2] = u.i[3] = 0;
        if (h == 0) u.v[0] = (_Float16)1.0f;
        oneF = u.v;
    }
    floatx16 wo0, wo1;
    {
        const floatx16* woG = (const floatx16*)(ws + OFF_D);
        wo0 = woG[h * 2 + 0];
        wo1 = woG[h * 2 + 1];
    }
    const float bov = bo[0];

    const int nbatch = (n + 63) >> 6;
    int b = blockIdx.x;
    if (b >= nbatch) return;

    // prime point prefetch
    float P0x, P0y, P0z, P1x, P1y, P1z;
    {
        int q0 = min(b * 64 + p, n - 1), q1 = min(b * 64 + 32 + p, n - 1);
        P0x = points[3 * q0]; P0y = points[3 * q0 + 1]; P0z = points[3 * q0 + 2];
        P1x = points[3 * q1]; P1y = points[3 * q1 + 1]; P1z = points[3 * q1 + 2];
    }

    while (true) {
        const int nb = b + (int)gridDim.x;
        const bool more = nb < nbatch;
        float N0x, N0y, N0z, N1x, N1y, N1z;
        N0x = N0y = N0z = N1x = N1y = N1z = 0.f;
        if (more) {
            int q0 = min(nb * 64 + p, n - 1), q1 = min(nb * 64 + 32 + p, n - 1);
            N0x = points[3 * q0]; N0y = points[3 * q0 + 1]; N0z = points[3 * q0 + 2];
            N1x = points[3 * q1]; N1y = points[3 * q1 + 1]; N1z = points[3 * q1 + 2];
        }

        // ---- layer 0 (bias via k=3 slot) ----
        floatx16 acc0[2], acc1[2];
        {
            FragU bu0, bu1;
            bu0.i[0] = bu0.i[1] = bu0.i[2] = bu0.i[3] = 0;
            bu1 = bu0;
            if (h == 0) {
                bu0.v[0] = (_Float16)P0x; bu0.v[1] = (_Float16)P0y;
                bu0.v[2] = (_Float16)P0z; bu0.v[3] = (_Float16)1.0f;
                bu1.v[0] = (_Float16)P1x; bu1.v[1] = (_Float16)P1y;
                bu1.v[2] = (_Float16)P1z; bu1.v[3] = (_Float16)1.0f;
            }
            acc0[0] = mfma16(W0a, bu0.v, (floatx16)(0.0f));
            acc0[1] = mfma16(W0b, bu0.v, (floatx16)(0.0f));
            acc1[0] = mfma16(W0a, bu1.v, (floatx16)(0.0f));
            acc1[1] = mfma16(W0b, bu1.v, (floatx16)(0.0f));
        }

        // ---- 6 hidden layers, JIT chunk pack + bias-broadcast MFMA ----
#pragma unroll
        for (int l = 0; l < N_HID; ++l) {
            floatx16 bc0 = mfma16(biasF[l][0], oneF, (floatx16)(0.0f));
            floatx16 bc1 = mfma16(biasF[l][1], oneF, (floatx16)(0.0f));
            floatx16 n00, n01, n10, n11;
#pragma unroll
            for (int s = 0; s < 4; ++s) {
                const int t = s >> 1, rpb = 4 * (s & 1);
                FragU f0, f1;
#pragma unroll
                for (int c = 0; c < 4; ++c) {
                    f0.i[c] = lrelu2(pkrtz(acc0[t][2 * (rpb + c)], acc0[t][2 * (rpb + c) + 1]));
                    f1.i[c] = lrelu2(pkrtz(acc1[t][2 * (rpb + c)], acc1[t][2 * (rpb + c) + 1]));
                }
                if (s == 0) {
                    n00 = mfma16(Wreg[l][0][0], f0.v, bc0);
                    n01 = mfma16(Wreg[l][1][0], f0.v, bc1);
                    n10 = mfma16(Wreg[l][0][0], f1.v, bc0);
                    n11 = mfma16(Wreg[l][1][0], f1.v, bc1);
                } else {
                    n00 = mfma16(Wreg[l][0][s], f0.v, n00);
                    n01 = mfma16(Wreg[l][1][s], f0.v, n01);
                    n10 = mfma16(Wreg[l][0][s], f1.v, n10);
                    n11 = mfma16(Wreg[l][1][s], f1.v, n11);
                }
            }
            acc0[0] = n00; acc0[1] = n01; acc1[0] = n10; acc1[1] = n11;
        }

        // ---- output: fp32 packed lrelu + dot with wo, cross-half reduce ----
        {
            float2v q0 = {0.f, 0.f}, q1 = {0.f, 0.f};
#pragma unroll
            for (int r2 = 0; r2 < 8; ++r2) {
                float2v w0p = { wo0[2 * r2], wo0[2 * r2 + 1] };
                float2v w1p = { wo1[2 * r2], wo1[2 * r2 + 1] };
                float2v u;
                u.x = acc0[0][2 * r2]; u.y = acc0[0][2 * r2 + 1];
                u = __builtin_elementwise_max(u, 0.2f * u);
                q0 += u * w0p;
                u.x = acc0[1][2 * r2]; u.y = acc0[1][2 * r2 + 1];
                u = __builtin_elementwise_max(u, 0.2f * u);
                q0 += u * w1p;
                u.x = acc1[0][2 * r2]; u.y = acc1[0][2 * r2 + 1];
                u = __builtin_elementwise_max(u, 0.2f * u);
                q1 += u * w0p;
                u.x = acc1[1][2 * r2]; u.y = acc1[1][2 * r2 + 1];
                u = __builtin_elementwise_max(u, 0.2f * u);
                q1 += u * w1p;
            }
            float part0 = q0.x + q0.y;
            float part1 = q1.x + q1.y;
            part0 += __shfl_xor(part0, 32);
            part1 += __shfl_xor(part1, 32);
            if (h == 0) {
                int pt0 = b * 64 + p, pt1 = b * 64 + 32 + p;
                if (pt0 < n) out[pt0] = part0 + bov;
                if (pt1 < n) out[pt1] = part1 + bov;
            }
        }

        if (!more) break;
        P0x = N0x; P0y = N0y; P0z = N0z;
        P1x = N1x; P1y = N1y; P1z = N1z;
        b = nb;
    }
}

extern "C" void kernel_launch(void* const* d_in, const int* in_sizes, int n_in,
                              void* d_out, int out_size, void* d_ws, size_t ws_size,
                              hipStream_t stream) {
    const float* points = (const float*)d_in[0];
    const float* w0     = (const float*)d_in[1];
    const float* s0     = (const float*)d_in[2];
    const float* b0     = (const float*)d_in[3];
    const float* wh     = (const float*)d_in[4];
    const float* sh     = (const float*)d_in[5];
    const float* bh     = (const float*)d_in[6];
    const float* wo     = (const float*)d_in[7];
    const float* so     = (const float*)d_in[8];
    const float* bo     = (const float*)d_in[9];

    const int n = in_sizes[0] / 3;

    setup_weights<<<(SETUP_TOTAL + 255) / 256, 256, 0, stream>>>(
        w0, s0, b0, wh, sh, bh, wo, so, (unsigned char*)d_ws);

    // 1024 persistent one-wave blocks; each handles nbatch/1024 batches.
    mlp_mfma<<<1024, 64, 0, stream>>>(
        points, (const unsigned char*)d_ws, bh, bo, (float*)d_out, n);
}